// Round 3
// baseline (308.515 us; speedup 1.0000x reference)
//
#include <hip/hip_runtime.h>
#include <stdint.h>

typedef unsigned int u32;
typedef unsigned short u16;

#define N_  1024
#define F_  512
#define ALPHA 0.2f
#define MSTR 36   // fallback kernel's LDS stride

typedef __attribute__((ext_vector_type(8))) short short8;
typedef __attribute__((ext_vector_type(4))) float float4v;

union Frag { short8 s; u32 u[4]; };

static __device__ __forceinline__ float bits2f(u32 b){ union{u32 u; float f;} c; c.u=b; return c.f; }
static __device__ __forceinline__ u32   f2bits(float f){ union{float f_; u32 u;} c; c.f_=f; return c.u; }
static __device__ __forceinline__ float bflo(u32 p){ return bits2f(p<<16); }
static __device__ __forceinline__ float bfhi(u32 p){ return bits2f(p & 0xffff0000u); }
static __device__ __forceinline__ u32   f2bf(float f){ u32 u=f2bits(f); return (u + 0x7fffu + ((u>>16)&1u))>>16; }

// ---- kernel 1: w1 = W^T a1, w2 = W^T a2 (atomic partial sums into ws[0..1024)) ----
__global__ void k_w12(const float* __restrict__ W, const float* __restrict__ a1,
                      const float* __restrict__ a2, float* __restrict__ ws){
    int t = threadIdx.x;          // 256 threads: f = t and t+256
    int bo = blockIdx.x;          // 64 blocks: o-chunk of 8
    float s1a=0.f,s2a=0.f,s1b=0.f,s2b=0.f;
    #pragma unroll
    for(int i=0;i<8;i++){
        int o = bo*8+i;
        float av1 = a1[o], av2 = a2[o];
        float wa = W[o*F_ + t], wb = W[o*F_ + t + 256];
        s1a += wa*av1; s2a += wa*av2; s1b += wb*av1; s2b += wb*av2;
    }
    atomicAdd(&ws[t],       s1a); atomicAdd(&ws[512+t],     s2a);
    atomicAdd(&ws[t+256],   s1b); atomicAdd(&ws[512+t+256], s2b);
}

// ---- kernel 2: per-row f1,f2 -> exp tables ----
// ws floats: [0,512) w1, [512,1024) w2; e1p/e1n fp32[16384]; e2pn u32[16384] (lo=bf16 e^f2, hi=bf16 e^{.2 f2})
__global__ void k_rowstats(const float* __restrict__ X, const float* __restrict__ ws,
                           float* __restrict__ e1p, float* __restrict__ e1n,
                           u32* __restrict__ e2pn){
    int lane = threadIdx.x & 63;
    int wv   = threadIdx.x >> 6;
    int r    = blockIdx.x*4 + wv;            // 0..16383
    float xf[8];
    float4 A  = *(const float4*)(X + (size_t)r*F_ + lane*8);
    float4 Bq = *(const float4*)(X + (size_t)r*F_ + lane*8 + 4);
    xf[0]=A.x; xf[1]=A.y; xf[2]=A.z; xf[3]=A.w;
    xf[4]=Bq.x; xf[5]=Bq.y; xf[6]=Bq.z; xf[7]=Bq.w;
    float4 wA = *(const float4*)(ws + lane*8);
    float4 wB = *(const float4*)(ws + lane*8 + 4);
    float4 vA = *(const float4*)(ws + 512 + lane*8);
    float4 vB = *(const float4*)(ws + 512 + lane*8 + 4);
    float d1 = xf[0]*wA.x + xf[1]*wA.y + xf[2]*wA.z + xf[3]*wA.w
             + xf[4]*wB.x + xf[5]*wB.y + xf[6]*wB.z + xf[7]*wB.w;
    float d2 = xf[0]*vA.x + xf[1]*vA.y + xf[2]*vA.z + xf[3]*vA.w
             + xf[4]*vB.x + xf[5]*vB.y + xf[6]*vB.z + xf[7]*vB.w;
    #pragma unroll
    for(int k=32;k>=1;k>>=1){ d1 += __shfl_xor(d1,k,64); d2 += __shfl_xor(d2,k,64); }
    if(lane==0){
        e1p[r] = __expf(d1);
        e1n[r] = __expf(ALPHA*d1);
        u32 lo = f2bf(__expf(d2));
        u32 hi = f2bf(__expf(ALPHA*d2));
        e2pn[r] = lo | (hi<<16);
    }
}

// ---- kernel 2b: global transpose X fp32 [b][m][f] -> XT bf16 [b][f][m] ----
__global__ __launch_bounds__(256)
void k_xt(const float* __restrict__ X, u16* __restrict__ XT){
    __shared__ u16 tile[64*72];   // [f_local][m_local], stride 72 u16
    const int t  = threadIdx.x;
    const int m0 = blockIdx.x*64, f0 = blockIdx.y*64, b = blockIdx.z;
    {
        const int ml = t>>4, fl4 = (t&15)*4;
        #pragma unroll
        for(int rr=0;rr<4;rr++){
            int m = ml + rr*16;
            float4 v = *(const float4*)(X + ((size_t)(b*N_ + m0 + m))*F_ + f0 + fl4);
            tile[(fl4+0)*72 + m] = (u16)f2bf(v.x);
            tile[(fl4+1)*72 + m] = (u16)f2bf(v.y);
            tile[(fl4+2)*72 + m] = (u16)f2bf(v.z);
            tile[(fl4+3)*72 + m] = (u16)f2bf(v.w);
        }
    }
    __syncthreads();
    {
        const int fl = t>>4, ml4 = (t&15)*4;
        #pragma unroll
        for(int rr=0;rr<4;rr++){
            int f = fl + rr*16;
            uint2 val = *(const uint2*)(&tile[f*72 + ml4]);
            *(uint2*)(XT + ((size_t)b*F_ + f0 + f)*N_ + m0 + ml4) = val;
        }
    }
}

// ---- kernel 3 (primary): fused scores+softmax+PV+ELU, B-frags straight from XT ----
// grid (32 n-blocks, 16 b), block 256 = 4 waves: (nsub 0/1) x (f-half 0/1).
// wave: 16 n-rows x 256 f. K-loop m in chunks of 32; adj prefetched 2 deep.
__global__ __launch_bounds__(256)
void k_main(const u16* __restrict__ XT, const int* __restrict__ adj,
            const float* __restrict__ e1p, const float* __restrict__ e1n,
            const u32* __restrict__ e2pn, float* __restrict__ out){
    __shared__ u32 lds_e2[N_];        // packed exp(f2) pairs for this batch, 4 KB

    const int t    = threadIdx.x;
    const int lane = t & 63;
    const int wv   = t >> 6;          // 0..3
    const int nsub = wv & 1;
    const int fh   = wv >> 1;
    const int b    = blockIdx.y;
    const int n0   = blockIdx.x * 32;
    const int r16  = lane & 15;
    const int quad = lane >> 4;
    const int nrow = n0 + nsub*16 + r16;

    ((uint4*)lds_e2)[t] = ((const uint4*)(e2pn + (size_t)b*N_))[t];

    const float e1pR = e1p[b*N_ + nrow];
    const float e1nR = e1n[b*N_ + nrow];
    const int* adjRow = adj + ((size_t)(b*N_ + nrow))*N_ + quad*8;
    const u16* XTb = XT + (size_t)b*F_*N_ + (size_t)(fh*256)*N_;   // [256 f][1024 m]

    float4v acc[16];
    #pragma unroll
    for(int i=0;i<16;i++) acc[i] = (float4v){0.f,0.f,0.f,0.f};
    float dsum = 0.f;

    __syncthreads();   // lds_e2 ready

    // adj prefetch, 2 chunks deep
    int adA[8], adB[8];
    *(int4*)(adA)   = *(const int4*)(adjRow);
    *(int4*)(adA+4) = *(const int4*)(adjRow + 4);
    *(int4*)(adB)   = *(const int4*)(adjRow + 32);
    *(int4*)(adB+4) = *(const int4*)(adjRow + 36);

    for(int m0=0; m0<N_; m0+=32){
        int pf = m0 + 64; if(pf >= N_) pf = 0;     // wrapped dummy prefetch on tail (unused)
        int adC[8];
        *(int4*)(adC)   = *(const int4*)(adjRow + pf);
        *(int4*)(adC+4) = *(const int4*)(adjRow + pf + 4);

        u32 ev[8];
        *(uint4*)(ev)   = *(const uint4*)(&lds_e2[m0 + quad*8]);
        *(uint4*)(ev+4) = *(const uint4*)(&lds_e2[m0 + quad*8 + 4]);

        u32 pb[8];
        #pragma unroll
        for(int j=0;j<8;j++){
            float pp = e1pR * bflo(ev[j]);   // exp(f1)*exp(f2)     = exp(s)
            float pn = e1nR * bfhi(ev[j]);   // exp(.2f1)*exp(.2f2) = exp(.2s)
            float p  = (pp > 1.0f) ? pp : pn;          // lrelu: s>0 <=> exp(s)>1
            p = (adA[j] != 0) ? p : 0.0f;
            dsum += p;
            pb[j] = f2bf(p);
        }
        Frag af;
        af.u[0] = pb[0] | (pb[1]<<16);
        af.u[1] = pb[2] | (pb[3]<<16);
        af.u[2] = pb[4] | (pb[5]<<16);
        af.u[3] = pb[6] | (pb[7]<<16);

        #pragma unroll
        for(int ct=0; ct<16; ct++){
            const u16* bp = XTb + (size_t)(ct*16 + r16)*N_ + m0 + quad*8;
            uint4 bw = *(const uint4*)bp;          // 8 contiguous m-values at fixed f
            Frag bf_;
            bf_.u[0]=bw.x; bf_.u[1]=bw.y; bf_.u[2]=bw.z; bf_.u[3]=bw.w;
            acc[ct] = __builtin_amdgcn_mfma_f32_16x16x32_bf16(af.s, bf_.s, acc[ct], 0, 0, 0);
        }
        #pragma unroll
        for(int j=0;j<8;j++){ adA[j] = adB[j]; adB[j] = adC[j]; }
    }

    // ---- softmax denominator: lane holds row (lane&15); reduce quads in-wave ----
    dsum += __shfl_xor(dsum, 16, 64);
    dsum += __shfl_xor(dsum, 32, 64);
    float invr[4];
    #pragma unroll
    for(int r=0;r<4;r++){
        float dr = __shfl(dsum, quad*4 + r, 64);
        invr[r] = 1.0f / fmaxf(dr, 1e-30f);
    }
    // ---- epilogue: scale, ELU, fp32 store ----
    #pragma unroll
    for(int ct=0; ct<16; ct++){
        #pragma unroll
        for(int r=0;r<4;r++){
            float v = acc[ct][r] * invr[r];
            v = (v > 0.f) ? v : (__expf(v) - 1.f);
            int n_out = n0 + nsub*16 + quad*4 + r;
            out[((size_t)(b*N_ + n_out))*F_ + fh*256 + ct*16 + r16] = v;
        }
    }
}

// ---- fallback (small ws): round-2 kernel, fp32 path, LDS-staged transpose ----
__global__ __launch_bounds__(128)
void k_main_fb(const float* __restrict__ X, const int* __restrict__ adj,
               const float* __restrict__ e1p, const float* __restrict__ e1n,
               const u32* __restrict__ e2pn, float* __restrict__ out){
    __shared__ u16 lds_xt[F_*MSTR];
    __shared__ u32 lds_e2[N_];
    const int t    = threadIdx.x;
    const int lane = t & 63;
    const int wv   = t >> 6;
    const int b    = blockIdx.y;
    const int n0   = blockIdx.x * 32;
    const int row16 = lane & 15;
    const int quad  = lane >> 4;
    const int n_row = n0 + wv*16 + row16;
    {
        const uint4* src = (const uint4*)(e2pn + (size_t)b*N_);
        uint4* dst = (uint4*)lds_e2;
        dst[t]     = src[t];
        dst[t+128] = src[t+128];
    }
    const float e1pR = e1p[b*N_ + n_row];
    const float e1nR = e1n[b*N_ + n_row];
    const int* adjRow = adj + ((size_t)(b*N_ + n_row))*N_ + quad*8;
    float4v acc[32];
    #pragma unroll
    for(int i=0;i<32;i++) acc[i] = (float4v){0.f,0.f,0.f,0.f};
    float dsum = 0.f;
    const int foBase = (t&7) + ((t>>6)<<3);
    const int uu     = (t>>3)&7;
    const float* Xf = X + (size_t)b*N_*F_;
    for(int m0=0; m0<N_; m0+=32){
        __syncthreads();
        #pragma unroll
        for(int q=0;q<4;q++){
            int fo = foBase + q*16;
            const float* sp = Xf + (size_t)(m0 + uu*4)*F_ + fo*8;
            float r0[8], r1[8], r2[8], r3[8];
            *(float4*)r0 = *(const float4*)sp;        *(float4*)(r0+4) = *(const float4*)(sp+4);
            *(float4*)r1 = *(const float4*)(sp+F_);   *(float4*)(r1+4) = *(const float4*)(sp+F_+4);
            *(float4*)r2 = *(const float4*)(sp+2*F_); *(float4*)(r2+4) = *(const float4*)(sp+2*F_+4);
            *(float4*)r3 = *(const float4*)(sp+3*F_); *(float4*)(r3+4) = *(const float4*)(sp+3*F_+4);
            #pragma unroll
            for(int j=0;j<8;j++){
                uint2 val;
                val.x = f2bf(r0[j]) | (f2bf(r1[j])<<16);
                val.y = f2bf(r2[j]) | (f2bf(r3[j])<<16);
                *(uint2*)(lds_xt + (size_t)(fo*8+j)*MSTR + uu*4) = val;
            }
        }
        __syncthreads();
        int ad[8];
        *(int4*)(ad)   = *(const int4*)(adjRow + m0);
        *(int4*)(ad+4) = *(const int4*)(adjRow + m0 + 4);
        u32 ev[8];
        *(uint4*)(ev)   = *(const uint4*)(&lds_e2[m0 + quad*8]);
        *(uint4*)(ev+4) = *(const uint4*)(&lds_e2[m0 + quad*8 + 4]);
        u32 pb[8];
        #pragma unroll
        for(int j=0;j<8;j++){
            float pp = e1pR * bflo(ev[j]);
            float pn = e1nR * bfhi(ev[j]);
            float p  = (pp > 1.0f) ? pp : pn;
            p = (ad[j] != 0) ? p : 0.0f;
            dsum += p;
            pb[j] = f2bf(p);
        }
        Frag af;
        af.u[0] = pb[0] | (pb[1]<<16);
        af.u[1] = pb[2] | (pb[3]<<16);
        af.u[2] = pb[4] | (pb[5]<<16);
        af.u[3] = pb[6] | (pb[7]<<16);
        #pragma unroll
        for(int ct=0; ct<32; ct++){
            const u16* bp = lds_xt + (size_t)(ct*16 + row16)*MSTR + quad*8;
            uint2 blo = *(const uint2*)bp;
            uint2 bhi = *(const uint2*)(bp + 4);
            Frag bf_;
            bf_.u[0]=blo.x; bf_.u[1]=blo.y; bf_.u[2]=bhi.x; bf_.u[3]=bhi.y;
            acc[ct] = __builtin_amdgcn_mfma_f32_16x16x32_bf16(af.s, bf_.s, acc[ct], 0, 0, 0);
        }
    }
    dsum += __shfl_xor(dsum, 16, 64);
    dsum += __shfl_xor(dsum, 32, 64);
    float invr[4];
    #pragma unroll
    for(int r=0;r<4;r++){
        float dr = __shfl(dsum, wv*0 + quad*4 + r, 16);  // row (quad*4+r) within this wave's 16 rows
        invr[r] = 1.0f / fmaxf(dr, 1e-30f);
    }
    #pragma unroll
    for(int ct=0; ct<32; ct++){
        #pragma unroll
        for(int r=0;r<4;r++){
            float v = acc[ct][r] * invr[r];
            v = (v > 0.f) ? v : (__expf(v) - 1.f);
            int n_out = n0 + wv*16 + quad*4 + r;
            out[((size_t)(b*N_ + n_out))*F_ + ct*16 + row16] = v;
        }
    }
}

extern "C" void kernel_launch(void* const* d_in, const int* in_sizes, int n_in,
                              void* d_out, int out_size, void* d_ws, size_t ws_size,
                              hipStream_t stream) {
    const float* X  = (const float*)d_in[0];   // [16,1024,512] fp32
    const int* adj  = (const int*)d_in[1];     // [16,1024,1024] int32
    const float* W  = (const float*)d_in[2];   // [512,512] fp32
    const float* a1 = (const float*)d_in[3];   // [512]
    const float* a2 = (const float*)d_in[4];   // [512]
    float* out = (float*)d_out;                // [16,1024,512] fp32
    float* ws  = (float*)d_ws;
    float* e1p = ws + 1024;
    float* e1n = ws + 1024 + 16384;
    u32*  e2pn = (u32*)(ws + 1024 + 32768);
    u16*  XT   = (u16*)(ws + 50176);           // 16 MB bf16 [b][f][m]
    const size_t need = (size_t)50176*4 + (size_t)16*F_*N_*2;

    hipMemsetAsync(ws, 0, 1024*sizeof(float), stream);
    k_w12<<<64, 256, 0, stream>>>(W, a1, a2, ws);
    k_rowstats<<<4096, 256, 0, stream>>>(X, ws, e1p, e1n, e2pn);
    if(ws_size >= need){
        k_xt<<<dim3(16, 8, 16), 256, 0, stream>>>(X, XT);
        k_main<<<dim3(32, 16), 256, 0, stream>>>(XT, adj, e1p, e1n, e2pn, out);
    } else {
        k_main_fb<<<dim3(32, 16), 128, 0, stream>>>(X, adj, e1p, e1n, e2pn, out);
    }
}

// Round 4
// 197.203 us; speedup vs baseline: 1.5645x; 1.5645x over previous
//
#include <hip/hip_runtime.h>
#include <stdint.h>

typedef unsigned int u32;
typedef unsigned short u16;

#define N_  1024
#define F_  512
#define ALPHA 0.2f
#define TSTR 68   // k_prep LDS tile stride (u16): 136 B rows -> uint2-aligned reads, ~4-way write conflicts

typedef __attribute__((ext_vector_type(8))) short short8;
typedef __attribute__((ext_vector_type(4))) float float4v;

union Frag { short8 s; u32 u[4]; };

static __device__ __forceinline__ float bits2f(u32 b){ union{u32 u; float f;} c; c.u=b; return c.f; }
static __device__ __forceinline__ u32   f2bits(float f){ union{float f_; u32 u;} c; c.f_=f; return c.u; }
static __device__ __forceinline__ float bflo(u32 p){ return bits2f(p<<16); }
static __device__ __forceinline__ float bfhi(u32 p){ return bits2f(p & 0xffff0000u); }
static __device__ __forceinline__ u32   f2bf(float f){ u32 u=f2bits(f); return (u + 0x7fffu + ((u>>16)&1u))>>16; }

// async global->LDS, 16 B per lane; LDS dest = wave-uniform base + lane*16
static __device__ __forceinline__ void gload_lds16(const void* g, void* l){
    __builtin_amdgcn_global_load_lds((const __attribute__((address_space(1))) u32*)g,
                                     (__attribute__((address_space(3))) u32*)l, 16, 0, 0);
}

// ---- kernel 1: w1 = W^T a1, w2 = W^T a2 (atomic partial sums into ws[0..1024)) ----
__global__ void k_w12(const float* __restrict__ W, const float* __restrict__ a1,
                      const float* __restrict__ a2, float* __restrict__ ws){
    int t = threadIdx.x;          // 256 threads: f = t and t+256
    int bo = blockIdx.x;          // 64 blocks: o-chunk of 8
    float s1a=0.f,s2a=0.f,s1b=0.f,s2b=0.f;
    #pragma unroll
    for(int i=0;i<8;i++){
        int o = bo*8+i;
        float av1 = a1[o], av2 = a2[o];
        float wa = W[o*F_ + t], wb = W[o*F_ + t + 256];
        s1a += wa*av1; s2a += wa*av2; s1b += wb*av1; s2b += wb*av2;
    }
    atomicAdd(&ws[t],       s1a); atomicAdd(&ws[512+t],     s2a);
    atomicAdd(&ws[t+256],   s1b); atomicAdd(&ws[512+t+256], s2b);
}

// ---- kernel 2: fused transpose + dot accumulation ----
// X fp32 [b][m][f] -> XT bf16 [b][f][m]; also d1acc[r] += X[r,:].w1, d2acc += X[r,:].w2 (fp32 atomics)
__global__ __launch_bounds__(256)
void k_prep(const float* __restrict__ X, const float* __restrict__ ws,
            u16* __restrict__ XT, float* __restrict__ d1acc, float* __restrict__ d2acc){
    __shared__ u16 tile[64*TSTR];
    const int t  = threadIdx.x;
    const int m0 = blockIdx.x*64, f0 = blockIdx.y*64, b = blockIdx.z;
    const int ml = t>>4, fl4 = (t&15)*4;
    float4 w1q = *(const float4*)(ws + f0 + fl4);
    float4 w2q = *(const float4*)(ws + 512 + f0 + fl4);
    float d1p[4], d2p[4];
    #pragma unroll
    for(int rr=0;rr<4;rr++){
        int m = ml + rr*16;
        float4 v = *(const float4*)(X + ((size_t)(b*N_ + m0 + m))*F_ + f0 + fl4);
        tile[(fl4+0)*TSTR + m] = (u16)f2bf(v.x);
        tile[(fl4+1)*TSTR + m] = (u16)f2bf(v.y);
        tile[(fl4+2)*TSTR + m] = (u16)f2bf(v.z);
        tile[(fl4+3)*TSTR + m] = (u16)f2bf(v.w);
        d1p[rr] = v.x*w1q.x + v.y*w1q.y + v.z*w1q.z + v.w*w1q.w;
        d2p[rr] = v.x*w2q.x + v.y*w2q.y + v.z*w2q.z + v.w*w2q.w;
    }
    #pragma unroll
    for(int s=1;s<16;s<<=1){
        #pragma unroll
        for(int rr=0;rr<4;rr++){ d1p[rr] += __shfl_xor(d1p[rr],s,64); d2p[rr] += __shfl_xor(d2p[rr],s,64); }
    }
    if((t&15)==0){
        #pragma unroll
        for(int rr=0;rr<4;rr++){
            atomicAdd(&d1acc[b*N_ + m0 + ml + rr*16], d1p[rr]);
            atomicAdd(&d2acc[b*N_ + m0 + ml + rr*16], d2p[rr]);
        }
    }
    __syncthreads();
    const int fl = t>>4, ml4 = (t&15)*4;
    #pragma unroll
    for(int rr=0;rr<4;rr++){
        int f = fl + rr*16;
        uint2 val = *(const uint2*)(&tile[f*TSTR + ml4]);
        *(uint2*)(XT + ((size_t)(b*F_ + f0 + f))*N_ + m0 + ml4) = val;
    }
}

// ---- kernel 3: d1,d2 -> exp tables (in place over d1acc/d2acc + separate e2pn) ----
__global__ void k_exp(float* __restrict__ d1e, float* __restrict__ d2e, u32* __restrict__ e2pn){
    int r = blockIdx.x*256 + threadIdx.x;
    float d1 = d1e[r], d2 = d2e[r];
    d1e[r] = __expf(d1);            // e1p
    d2e[r] = __expf(ALPHA*d1);      // e1n
    u32 lo = f2bf(__expf(d2));
    u32 hi = f2bf(__expf(ALPHA*d2));
    e2pn[r] = lo | (hi<<16);
}

// ---- kernel 4: fused scores+softmax+PV+ELU ----
// grid (16 n-blocks, 16 b), block 512 = 8 waves: (nsub 0..3) x (fh 0/1).
// wave: 16 n-rows x 256 f. m-chunks of 32, double-buffered async LDS staging of XT.
__global__ __launch_bounds__(512, 2)
void k_main(const u16* __restrict__ XT, const int* __restrict__ adj,
            const float* __restrict__ e1p, const float* __restrict__ e1n,
            const u32* __restrict__ e2pn, float* __restrict__ out){
    __shared__ u16 xbuf[2][2][8192];   // [dbuf][fh][16 ct * 512 u16], 64 KB
    __shared__ u32 lds_e2[N_];         // 4 KB

    const int t    = threadIdx.x;
    const int lane = t & 63;
    const int wv   = t >> 6;           // 0..7
    const int nsub = wv & 3;
    const int fh   = wv >> 2;
    const int b    = blockIdx.y;
    const int n0   = blockIdx.x * 64;
    const int r16  = lane & 15;
    const int quad = lane >> 4;
    const int nrow = n0 + nsub*16 + r16;

    if(t < 256) ((uint4*)lds_e2)[t] = ((const uint4*)(e2pn + (size_t)b*N_))[t];

    const float e1pR = e1p[b*N_ + nrow];
    const float e1nR = e1n[b*N_ + nrow];
    const int* adjRow = adj + ((size_t)(b*N_ + nrow))*N_ + quad*8;
    const u16* XTb = XT + (size_t)b*F_*N_;

    // stage chunk 0 -> buf 0 (32 calls split over 8 waves; lane l covers f=c*16+(l&15), m=(l>>4)*8)
    #pragma unroll
    for(int k=0;k<4;k++){
        int idx = wv*4 + k, fhh = idx>>4, c = idx&15;
        const u16* g = XTb + (size_t)(fhh*256 + c*16 + r16)*N_ + quad*8;
        gload_lds16(g, &xbuf[0][fhh][c*512]);
    }

    float4v acc[16];
    #pragma unroll
    for(int i=0;i<16;i++) acc[i] = (float4v){0.f,0.f,0.f,0.f};
    float dsum = 0.f;

    int adA[8], adB[8];
    *(int4*)(adA)   = *(const int4*)(adjRow);
    *(int4*)(adA+4) = *(const int4*)(adjRow + 4);
    *(int4*)(adB)   = *(const int4*)(adjRow + 32);
    *(int4*)(adB+4) = *(const int4*)(adjRow + 36);

    int db = 0;
    for(int i=0;i<32;i++){
        const int m0 = i*32;
        __syncthreads();               // staging for xbuf[db] complete (vmcnt drain at barrier)
        if(i < 31){
            const int ms = m0 + 32;
            #pragma unroll
            for(int k=0;k<4;k++){
                int idx = wv*4 + k, fhh = idx>>4, c = idx&15;
                const u16* g = XTb + (size_t)(fhh*256 + c*16 + r16)*N_ + ms + quad*8;
                gload_lds16(g, &xbuf[db^1][fhh][c*512]);
            }
        }
        int pf = (i < 30) ? (m0 + 64) : 0;      // dummy wrap on tail (unused)
        int adC[8];
        *(int4*)(adC)   = *(const int4*)(adjRow + pf);
        *(int4*)(adC+4) = *(const int4*)(adjRow + pf + 4);

        u32 ev[8];
        *(uint4*)(ev)   = *(const uint4*)(&lds_e2[m0 + quad*8]);
        *(uint4*)(ev+4) = *(const uint4*)(&lds_e2[m0 + quad*8 + 4]);

        u32 pb[8];
        #pragma unroll
        for(int j=0;j<8;j++){
            float pp = e1pR * bflo(ev[j]);   // exp(f1)*exp(f2)     = exp(s)
            float pn = e1nR * bfhi(ev[j]);   // exp(.2f1)*exp(.2f2) = exp(.2s)
            float p  = (pp > 1.0f) ? pp : pn;          // lrelu: s>0 <=> exp(s)>1
            p = (adA[j] != 0) ? p : 0.0f;
            dsum += p;
            pb[j] = f2bf(p);
        }
        Frag af;
        af.u[0] = pb[0] | (pb[1]<<16);
        af.u[1] = pb[2] | (pb[3]<<16);
        af.u[2] = pb[4] | (pb[5]<<16);
        af.u[3] = pb[6] | (pb[7]<<16);

        const u16* bb = &xbuf[db][fh][lane*8];   // lane-linear: conflict-free ds_read_b128
        #pragma unroll
        for(int ct=0; ct<16; ct++){
            uint4 bw = *(const uint4*)(bb + ct*512);
            Frag bf_;
            bf_.u[0]=bw.x; bf_.u[1]=bw.y; bf_.u[2]=bw.z; bf_.u[3]=bw.w;
            acc[ct] = __builtin_amdgcn_mfma_f32_16x16x32_bf16(af.s, bf_.s, acc[ct], 0, 0, 0);
        }
        #pragma unroll
        for(int j=0;j<8;j++){ adA[j] = adB[j]; adB[j] = adC[j]; }
        db ^= 1;
    }

    // ---- softmax denominator: in-wave reduce over quads, broadcast to C-layout rows ----
    dsum += __shfl_xor(dsum, 16, 64);
    dsum += __shfl_xor(dsum, 32, 64);
    float invr[4];
    #pragma unroll
    for(int r=0;r<4;r++){
        float dr = __shfl(dsum, quad*4 + r, 64);
        invr[r] = 1.0f / fmaxf(dr, 1e-30f);
    }
    // ---- epilogue: scale, ELU, fp32 store ----
    #pragma unroll
    for(int ct=0; ct<16; ct++){
        #pragma unroll
        for(int r=0;r<4;r++){
            float v = acc[ct][r] * invr[r];
            v = (v > 0.f) ? v : (__expf(v) - 1.f);
            int n_out = n0 + nsub*16 + quad*4 + r;
            out[((size_t)(b*N_ + n_out))*F_ + fh*256 + ct*16 + r16] = v;
        }
    }
}

extern "C" void kernel_launch(void* const* d_in, const int* in_sizes, int n_in,
                              void* d_out, int out_size, void* d_ws, size_t ws_size,
                              hipStream_t stream) {
    const float* X  = (const float*)d_in[0];   // [16,1024,512] fp32
    const int* adj  = (const int*)d_in[1];     // [16,1024,1024] int32
    const float* W  = (const float*)d_in[2];   // [512,512] fp32
    const float* a1 = (const float*)d_in[3];   // [512]
    const float* a2 = (const float*)d_in[4];   // [512]
    float* out = (float*)d_out;                // [16,1024,512] fp32

    float* ws   = (float*)d_ws;
    float* d1e  = ws + 1024;                   // d1acc -> e1p (in place)
    float* d2e  = ws + 1024 + 16384;           // d2acc -> e1n (in place)
    u32*  e2pn  = (u32*)(ws + 1024 + 32768);
    u16*  XT    = (u16*)(ws + 50176);          // 16.78 MB bf16 [b][f][m]

    hipMemsetAsync(ws, 0, 33792*sizeof(float), stream);   // zero w1/w2 + d1acc + d2acc
    k_w12<<<64, 256, 0, stream>>>(W, a1, a2, ws);
    k_prep<<<dim3(16, 8, 16), 256, 0, stream>>>(X, ws, XT, d1e, d2e);
    k_exp<<<64, 256, 0, stream>>>(d1e, d2e, e2pn);
    k_main<<<dim3(16, 16), 512, 0, stream>>>(XT, adj, d1e, d2e, e2pn, out);
}